// Round 11
// baseline (130.734 us; speedup 1.0000x reference)
//
#include <hip/hip_runtime.h>
#include <math.h>

#define HH 256
#define WW 256
#define BB 8
#define MM 256
#define NN (HH * WW)

#define EPSI 1e-6f
#define MAXD 362.03867196751236f
#define EPS_OVER_MAXD (1e-6f / 362.03867196751236f)

static __device__ __forceinline__ float asqrt(float x) {
    return __builtin_amdgcn_sqrtf(x);     // single v_sqrt_f32
}

// ws layout (u32 units):
//   [0..15]                    sums (float s0,s1 per batch)
//   [16 .. 16+2048)            gmin, INVERTED float bits (0 == +inf)
//   [2064 .. +B*NN)            sc table: 1/(p^4+EPS/MAXD) per (b,n)     (2 MB)
//   [2064+B*NN .. +2*B*NN)     geo table: (gx, ey) per (b,row,m) float2 (4 MB)
#define WS_GMIN 16
#define WS_SC   2064
#define WS_GEO  (WS_SC + BB * NN)

// ---------------------------------------------------------------------------
// prep: sc table + per-(b,row,m) geometry table. ~6 MB writes, memory-bound.
// ---------------------------------------------------------------------------
__global__ __launch_bounds__(256) void whd_prep(
    const float* __restrict__ pm, const float* __restrict__ gt,
    const float* __restrict__ osz, float* __restrict__ sc,
    float2* __restrict__ geo)
{
    const int idx = blockIdx.x * 256 + threadIdx.x;   // 0 .. B*NN-1

    // sc[b][n]
    const float p  = pm[idx];
    const float p2 = p * p;
    sc[idx] = 1.0f / fmaf(p2, p2, EPS_OVER_MAXD);

    // geo[b][row][m] = (gx*nfX, ((row*nfY) - gy*nfY)^2)
    const int b   = idx >> 16;
    const int row = (idx >> 8) & 255;
    const int m   = idx & 255;
    const float nfY = osz[b * 2 + 0] * (1.0f / HH);
    const float nfX = osz[b * 2 + 1] * (1.0f / WW);
    const float2 g  = ((const float2*)gt)[b * MM + m];   // coalesced (m fastest)
    const float  gx = g.y * nfX;
    const float  dy = (float)row * nfY - g.x * nfY;
    geo[idx] = make_float2(gx, dy * dy);
}

// ---------------------------------------------------------------------------
// main: one row per block (2048 blocks = 8/CU = 8 waves/SIMD).
// ALL in-loop loads are wave-uniform -> scalar pipe (s_load); zero LDS,
// zero atomics in loops; fire-and-forget merges at the end.
// ---------------------------------------------------------------------------
__global__ __launch_bounds__(256, 8) void whd_main(
    const float* __restrict__ pm, const float* __restrict__ osz,
    const float* __restrict__ sc, const float2* __restrict__ geo,
    float* __restrict__ sums, unsigned* __restrict__ gmin)
{
    __shared__ float swred[8];

    const int tid = threadIdx.x;
    const int row = blockIdx.x;   // 0..255
    const int b   = blockIdx.y;

    const float nfX = osz[b * 2 + 1] * (1.0f / WW);
    const float x   = (float)tid * nfX;
    const float p   = pm[b * NN + row * WW + tid];       // own pixel (coalesced)

    const float2* gb = geo + (b * HH + row) * MM;        // uniform base

    // ---- Phase A: pixel col=tid; min_m d^2. 3 VALU per m (sub,fmaf,fmin),
    // geo reads wave-uniform -> s_load; 4 independent fmin chains.
    float a0 = INFINITY, a1 = INFINITY, a2 = INFINITY, a3 = INFINITY;
    #pragma unroll 8
    for (int m = 0; m < MM; m += 4) {
        const float2 g0 = gb[m];
        const float2 g1 = gb[m + 1];
        const float2 g2 = gb[m + 2];
        const float2 g3 = gb[m + 3];
        const float dx0 = x - g0.x;
        const float dx1 = x - g1.x;
        const float dx2 = x - g2.x;
        const float dx3 = x - g3.x;
        a0 = fminf(a0, fmaf(dx0, dx0, g0.y));
        a1 = fminf(a1, fmaf(dx1, dx1, g1.y));
        a2 = fminf(a2, fmaf(dx2, dx2, g2.y));
        a3 = fminf(a3, fmaf(dx3, dx3, g3.y));
    }
    const float mind2 = fminf(fminf(a0, a1), fminf(a2, a3));

    // ---- Phase B: thread owns m=tid; min over this row's 256 pixels of
    // (sqrt(d2)+EPS)*sc. sc reads wave-uniform -> s_load. Body keeps every
    // VALU op at <=1 SGPR operand: fmaf(v,v,v_ey), sqrt, add(lit), mul(s_sc).
    const float2 gm = gb[tid];            // per-lane load, once
    const float  ey = gm.y;
    const float* scp = sc + b * NN + row * WW;           // uniform base

    float c0 = INFINITY, c1 = INFINITY;
    float dxA = 0.0f - gm.x;
    float dxB = nfX - gm.x;
    const float st = 2.0f * nfX;
    #pragma unroll 8
    for (int c = 0; c < WW; c += 2) {
        const float s0 = scp[c];
        const float s1 = scp[c + 1];
        const float d0 = fmaf(dxA, dxA, ey);
        const float d1 = fmaf(dxB, dxB, ey);
        c0 = fminf(c0, (asqrt(d0) + EPSI) * s0);
        c1 = fminf(c1, (asqrt(d1) + EPSI) * s1);
        dxA += st;
        dxB += st;
    }
    const float cmin = fminf(c0, c1);

    // ---- term1 partials (thread-exclusive pixel), one wave reduce
    float sum0 = p;
    float sum1 = p * asqrt(mind2);
    #pragma unroll
    for (int off = 32; off; off >>= 1) {
        sum0 += __shfl_down(sum0, off, 64);
        sum1 += __shfl_down(sum1, off, 64);
    }
    if ((tid & 63) == 0) { swred[(tid >> 6) * 2] = sum0; swred[(tid >> 6) * 2 + 1] = sum1; }
    __syncthreads();

    // fire-and-forget merges — no fence, no counter, no waiting
    if (tid == 0) {
        const float s0 = (swred[0] + swred[2]) + (swred[4] + swred[6]);
        const float s1 = (swred[1] + swred[3]) + (swred[5] + swred[7]);
        atomicAdd(&sums[b * 2 + 0], s0);
        atomicAdd(&sums[b * 2 + 1], s1);
    }
    atomicMax(&gmin[b * MM + tid], ~__float_as_uint(cmin));
}

// ---------------------------------------------------------------------------
__global__ __launch_bounds__(256) void whd_final(const float* __restrict__ sums,
                                                 const unsigned* __restrict__ gmin,
                                                 float* __restrict__ out) {
    __shared__ float gred[4];
    const int tid = threadIdx.x;

    float gacc = 0.0f;
    #pragma unroll
    for (int q = 0; q < BB; ++q) {
        const float v = __uint_as_float(~gmin[q * MM + tid]);
        gacc += fminf(fmaxf(v, 0.0f), MAXD);
    }
    #pragma unroll
    for (int off = 32; off; off >>= 1) gacc += __shfl_down(gacc, off, 64);
    if ((tid & 63) == 0) gred[tid >> 6] = gacc;
    __syncthreads();
    if (tid == 0) {
        float t1 = 0.0f;
        #pragma unroll
        for (int q = 0; q < BB; ++q)
            t1 += sums[q * 2 + 1] / (sums[q * 2 + 0] + EPSI);
        const float g2 = (gred[0] + gred[1]) + (gred[2] + gred[3]);
        out[0] = t1 * (1.0f / BB) + g2 * (1.0f / (BB * MM));
    }
}

// ---------------------------------------------------------------------------
extern "C" void kernel_launch(void* const* d_in, const int* in_sizes, int n_in,
                              void* d_out, int out_size, void* d_ws, size_t ws_size,
                              hipStream_t stream) {
    const float* pm  = (const float*)d_in[0];   // [B, H, W]
    const float* gt  = (const float*)d_in[1];   // [B, M, 2]
    const float* osz = (const float*)d_in[2];   // [B, 2]
    float* out = (float*)d_out;

    unsigned* ws0  = (unsigned*)d_ws;
    float*    sums = (float*)ws0;
    unsigned* gmin = ws0 + WS_GMIN;
    float*    sct  = (float*)(ws0 + WS_SC);
    float2*   geo  = (float2*)(ws0 + WS_GEO);

    // zero-init sums + gmin only (0 == +inf in inverted representation)
    hipMemsetAsync(ws0, 0, (WS_GMIN + BB * MM) * sizeof(unsigned), stream);

    whd_prep<<<BB * NN / 256, 256, 0, stream>>>(pm, gt, osz, sct, geo);

    dim3 grid(HH, BB);
    whd_main<<<grid, 256, 0, stream>>>(pm, osz, sct, geo, sums, gmin);

    whd_final<<<1, 256, 0, stream>>>(sums, gmin, out);
}

// Round 12
// 105.268 us; speedup vs baseline: 1.2419x; 1.2419x over previous
//
#include <hip/hip_runtime.h>
#include <math.h>

#define HH 256
#define WW 256
#define BB 8
#define MM 256
#define NN (HH * WW)
#define ROWS 2
#define BLKS_PER_B (HH / ROWS)            // 128 -> grid 1024 = 4 blocks/CU

#define EPSI 1e-6f
#define MAXD 362.03867196751236f
#define EPS_OVER_MAXD (1e-6f / 362.03867196751236f)

static __device__ __forceinline__ float asqrt(float x) {
    return __builtin_amdgcn_sqrtf(x);     // single v_sqrt_f32
}

// ws layout (u32 units):
//   [0..15]                  sums (float s0,s1 per batch)
//   [16 .. 16+2048)          gmin, INVERTED float bits (0 == +inf)
//   [2064 .. +B*NN)          sc table: 1/(p^4+EPS/MAXD) per (b,n)  (2 MB)
//   [.. +2*B*MM)             gts: prescaled (gy*nfY, gx*nfX) per (b,m) (16 KB, hot)
//   [.. +B*MM)               gxs: gx*nfX per (b,m)                   (8 KB, hot)
#define WS_GMIN 16
#define WS_SC   2064
#define WS_GTS  (WS_SC + BB * NN)
#define WS_GXS  (WS_GTS + 2 * BB * MM)

// ---------------------------------------------------------------------------
// prep: sc table + small hot GT tables. ~2 MB writes, memory-bound, ~4 us.
// ---------------------------------------------------------------------------
__global__ __launch_bounds__(256) void whd_prep(
    const float* __restrict__ pm, const float* __restrict__ gt,
    const float* __restrict__ osz, float* __restrict__ sc,
    float2* __restrict__ gts, float* __restrict__ gxs)
{
    const int idx = blockIdx.x * 256 + threadIdx.x;   // 0 .. B*NN-1
    const float p  = pm[idx];
    const float p2 = p * p;
    sc[idx] = 1.0f / fmaf(p2, p2, EPS_OVER_MAXD);

    if (idx < BB * MM) {
        const int b = idx >> 8;
        const float nfY = osz[b * 2 + 0] * (1.0f / HH);
        const float nfX = osz[b * 2 + 1] * (1.0f / WW);
        const float2 g = ((const float2*)gt)[idx];
        gts[idx] = make_float2(g.x * nfY, g.y * nfX);
        gxs[idx] = g.y * nfX;
    }
}

// ---------------------------------------------------------------------------
// main: 2 rows/block, 1024 blocks = 4/CU. Phase A: LDS ey-table (128 b128
// broadcast reads/wave) + hot gxs via s_load. Phase B: pure scalar sc reads,
// zero DS. No atomics/cross-lane in loops; fire-and-forget merges.
// ---------------------------------------------------------------------------
__global__ __launch_bounds__(256, 4) void whd_main(
    const float* __restrict__ pm, const float* __restrict__ osz,
    const float* __restrict__ sc, const float2* __restrict__ gts,
    const float* __restrict__ gxs,
    float* __restrict__ sums, unsigned* __restrict__ gmin)
{
    __shared__ __align__(16) float2 sey[MM];   // (ey_row0, ey_row1) per m, 2 KB
    __shared__ float swred[8];

    const int tid = threadIdx.x;
    const int blk = blockIdx.x;   // 0..127
    const int b   = blockIdx.y;

    const float nfY = osz[b * 2 + 0] * (1.0f / HH);
    const float nfX = osz[b * 2 + 1] * (1.0f / WW);
    const int   r0  = blk * ROWS;
    const float y0  = (float)r0 * nfY;
    const float y1  = y0 + nfY;
    const float x   = (float)tid * nfX;

    // own pixels (coalesced)
    const float p0 = pm[b * NN + r0 * WW + tid];
    const float p1 = pm[b * NN + (r0 + 1) * WW + tid];

    // staging: thread tid owns GT m=tid -> ey per row into LDS + regs
    const float2 gm  = gts[b * MM + tid];     // per-lane, once
    const float  gxm = gm.y;
    const float  dy0 = y0 - gm.x, dy1 = y1 - gm.x;
    const float  ey0 = dy0 * dy0,  ey1 = dy1 * dy1;
    sey[tid] = make_float2(ey0, ey1);
    __syncthreads();

    // ---- Phase A: pixel col=tid (both rows); min_m d^2.
    // 1 ds_read_b128 per 2 m (broadcast) + gx from s_load; 2.5 VALU/pair.
    const float*  gxb  = gxs + b * MM;        // uniform base -> s_load
    const float4* sey4 = (const float4*)sey;  // (ey0_m, ey1_m, ey0_m+1, ey1_m+1)
    float a00 = INFINITY, a01 = INFINITY;     // row0 chains
    float a10 = INFINITY, a11 = INFINITY;     // row1 chains
    #pragma unroll 8
    for (int k = 0; k < MM / 2; ++k) {
        const float4 e  = sey4[k];
        const float gx0 = gxb[2 * k];         // s_load (scalar pipe)
        const float gx1 = gxb[2 * k + 1];
        const float dx0 = x - gx0;
        const float dx1 = x - gx1;
        a00 = fminf(a00, fmaf(dx0, dx0, e.x));
        a10 = fminf(a10, fmaf(dx0, dx0, e.y));
        a01 = fminf(a01, fmaf(dx1, dx1, e.z));
        a11 = fminf(a11, fmaf(dx1, dx1, e.w));
    }
    const float mind2r0 = fminf(a00, a01);
    const float mind2r1 = fminf(a10, a11);

    // ---- Phase B: thread owns m=tid (gxm/ey0/ey1 in regs); min over the
    // block's 512 pixels of (sqrt(d2)+EPS)*sc. sc wave-uniform -> s_load;
    // zero DS. Every VALU op has <=1 SGPR operand.
    const float* sc0p = sc + b * NN + r0 * WW;   // uniform bases
    const float* sc1p = sc0p + WW;

    float c0 = INFINITY, c1 = INFINITY;
    float dx = 0.0f - gxm;
    #pragma unroll 8
    for (int c = 0; c < WW; ++c) {
        const float s0 = sc0p[c];             // s_load
        const float s1 = sc1p[c];
        const float d0 = fmaf(dx, dx, ey0);
        const float d1 = fmaf(dx, dx, ey1);
        c0 = fminf(c0, (asqrt(d0) + EPSI) * s0);
        c1 = fminf(c1, (asqrt(d1) + EPSI) * s1);
        dx += nfX;
    }
    const float cmin = fminf(c0, c1);

    // ---- term1 partials (thread-exclusive pixels), one wave reduce
    float sum0 = p0 + p1;
    float sum1 = fmaf(p0, asqrt(mind2r0), p1 * asqrt(mind2r1));
    #pragma unroll
    for (int off = 32; off; off >>= 1) {
        sum0 += __shfl_down(sum0, off, 64);
        sum1 += __shfl_down(sum1, off, 64);
    }
    if ((tid & 63) == 0) { swred[(tid >> 6) * 2] = sum0; swred[(tid >> 6) * 2 + 1] = sum1; }
    __syncthreads();

    // fire-and-forget merges — no fence, no counter, no waiting
    if (tid == 0) {
        const float s0 = (swred[0] + swred[2]) + (swred[4] + swred[6]);
        const float s1 = (swred[1] + swred[3]) + (swred[5] + swred[7]);
        atomicAdd(&sums[b * 2 + 0], s0);
        atomicAdd(&sums[b * 2 + 1], s1);
    }
    atomicMax(&gmin[b * MM + tid], ~__float_as_uint(cmin));
}

// ---------------------------------------------------------------------------
__global__ __launch_bounds__(256) void whd_final(const float* __restrict__ sums,
                                                 const unsigned* __restrict__ gmin,
                                                 float* __restrict__ out) {
    __shared__ float gred[4];
    const int tid = threadIdx.x;

    float gacc = 0.0f;
    #pragma unroll
    for (int q = 0; q < BB; ++q) {
        const float v = __uint_as_float(~gmin[q * MM + tid]);
        gacc += fminf(fmaxf(v, 0.0f), MAXD);
    }
    #pragma unroll
    for (int off = 32; off; off >>= 1) gacc += __shfl_down(gacc, off, 64);
    if ((tid & 63) == 0) gred[tid >> 6] = gacc;
    __syncthreads();
    if (tid == 0) {
        float t1 = 0.0f;
        #pragma unroll
        for (int q = 0; q < BB; ++q)
            t1 += sums[q * 2 + 1] / (sums[q * 2 + 0] + EPSI);
        const float g2 = (gred[0] + gred[1]) + (gred[2] + gred[3]);
        out[0] = t1 * (1.0f / BB) + g2 * (1.0f / (BB * MM));
    }
}

// ---------------------------------------------------------------------------
extern "C" void kernel_launch(void* const* d_in, const int* in_sizes, int n_in,
                              void* d_out, int out_size, void* d_ws, size_t ws_size,
                              hipStream_t stream) {
    const float* pm  = (const float*)d_in[0];   // [B, H, W]
    const float* gt  = (const float*)d_in[1];   // [B, M, 2]
    const float* osz = (const float*)d_in[2];   // [B, 2]
    float* out = (float*)d_out;

    unsigned* ws0  = (unsigned*)d_ws;
    float*    sums = (float*)ws0;
    unsigned* gmin = ws0 + WS_GMIN;
    float*    sct  = (float*)(ws0 + WS_SC);
    float2*   gts  = (float2*)(ws0 + WS_GTS);
    float*    gxs  = (float*)(ws0 + WS_GXS);

    // zero-init sums + gmin only (0 == +inf in inverted representation)
    hipMemsetAsync(ws0, 0, (WS_GMIN + BB * MM) * sizeof(unsigned), stream);

    whd_prep<<<BB * NN / 256, 256, 0, stream>>>(pm, gt, osz, sct, gts, gxs);

    dim3 grid(BLKS_PER_B, BB);
    whd_main<<<grid, 256, 0, stream>>>(pm, osz, sct, gts, gxs, sums, gmin);

    whd_final<<<1, 256, 0, stream>>>(sums, gmin, out);
}

// Round 13
// 101.765 us; speedup vs baseline: 1.2847x; 1.0344x over previous
//
#include <hip/hip_runtime.h>
#include <math.h>

#define HH 256
#define WW 256
#define BB 8
#define MM 256
#define NN (HH * WW)
#define ROWS 2
#define BLKS_PER_B (HH / ROWS)            // 128 -> grid 1024 = 4 blocks/CU

#define EPSI 1e-6f
#define MAXD 362.03867196751236f
#define EPS_OVER_MAXD (1e-6f / 362.03867196751236f)

static __device__ __forceinline__ float asqrt(float x) {
    return __builtin_amdgcn_sqrtf(x);     // single v_sqrt_f32
}
static __device__ __forceinline__ float min3(float a, float b, float c) {
    return fminf(fminf(a, b), c);         // folds to v_min3_f32
}

// ws layout (u32 units):
//   [0..15]                  sums (float s0,s1 per batch)
//   [16 .. 16+2048)          gmin, INVERTED float bits (0 == +inf)
//   [2064 .. +B*NN)          sc2 table: (1/(p^4+EPS/MAXD))^2 per (b,n) (2 MB)
//   [.. +2*B*MM)             gts: prescaled (gy*nfY, gx*nfX) per (b,m) (16 KB)
//   [.. +B*MM)               gxs: gx*nfX per (b,m)                     (8 KB)
#define WS_GMIN 16
#define WS_SC   2064
#define WS_GTS  (WS_SC + BB * NN)
#define WS_GXS  (WS_GTS + 2 * BB * MM)

// ---------------------------------------------------------------------------
// prep: sc^2 table + small hot GT tables. ~2 MB writes, memory-bound.
// ---------------------------------------------------------------------------
__global__ __launch_bounds__(256) void whd_prep(
    const float* __restrict__ pm, const float* __restrict__ gt,
    const float* __restrict__ osz, float* __restrict__ sc2,
    float2* __restrict__ gts, float* __restrict__ gxs)
{
    const int idx = blockIdx.x * 256 + threadIdx.x;   // 0 .. B*NN-1
    const float p  = pm[idx];
    const float p2 = p * p;
    const float s  = 1.0f / fmaf(p2, p2, EPS_OVER_MAXD);
    sc2[idx] = s * s;                     // squared: Phase B ranks by d^2*sc^2

    if (idx < BB * MM) {
        const int b = idx >> 8;
        const float nfY = osz[b * 2 + 0] * (1.0f / HH);
        const float nfX = osz[b * 2 + 1] * (1.0f / WW);
        const float2 g = ((const float2*)gt)[idx];
        gts[idx] = make_float2(g.x * nfY, g.y * nfX);
        gxs[idx] = g.y * nfX;
    }
}

// ---------------------------------------------------------------------------
// main: 2 rows/block, 1024 blocks = 4/CU. Phase A: LDS ey-pairs (b128
// broadcast) + hot gxs via s_load. Phase B: sqrt-free t=d2*sc2 ranking with
// scalar sc2 reads. min3 chains + distance-1 prefetch everywhere.
// ---------------------------------------------------------------------------
__global__ __launch_bounds__(256, 4) void whd_main(
    const float* __restrict__ pm, const float* __restrict__ osz,
    const float* __restrict__ sc2, const float2* __restrict__ gts,
    const float* __restrict__ gxs,
    float* __restrict__ sums, unsigned* __restrict__ gmin)
{
    __shared__ __align__(16) float2 sey[MM];   // (ey_row0, ey_row1) per m, 2 KB
    __shared__ float swred[8];

    const int tid = threadIdx.x;
    const int blk = blockIdx.x;   // 0..127
    const int b   = blockIdx.y;

    const float nfY = osz[b * 2 + 0] * (1.0f / HH);
    const float nfX = osz[b * 2 + 1] * (1.0f / WW);
    const int   r0  = blk * ROWS;
    const float y0  = (float)r0 * nfY;
    const float y1  = y0 + nfY;
    const float x   = (float)tid * nfX;

    // own pixels (coalesced)
    const float p0 = pm[b * NN + r0 * WW + tid];
    const float p1 = pm[b * NN + (r0 + 1) * WW + tid];

    // staging: thread tid owns GT m=tid -> ey per row into LDS + regs
    const float2 gm  = gts[b * MM + tid];     // per-lane, once
    const float  gxm = gm.y;
    const float  dy0 = y0 - gm.x, dy1 = y1 - gm.x;
    const float  ey0 = dy0 * dy0,  ey1 = dy1 * dy1;
    sey[tid] = make_float2(ey0, ey1);
    __syncthreads();

    // ---- Phase A: pixel col=tid (both rows); min_m d^2. 4 m per iter:
    // 2 LDS b128 (broadcast) + 1 scalar float4 of gx; 16 VALU / 8 pairs.
    const float4* sey4 = (const float4*)sey;          // 128 entries
    const float4* gx4p = (const float4*)(gxs + b * MM); // 64 entries, hot
    float4 e0 = sey4[0], e1 = sey4[1];
    float4 gx = gx4p[0];
    float a0 = INFINITY, a1 = INFINITY;    // row0 chains
    float b0 = INFINITY, b1 = INFINITY;    // row1 chains
    #pragma unroll 2
    for (int k = 0; k < MM / 4; ++k) {
        const int kn = (k + 1) & 63;
        const float4 ne0 = sey4[2 * kn];
        const float4 ne1 = sey4[2 * kn + 1];
        const float4 ngx = gx4p[kn];
        const float dx0 = x - gx.x;
        const float dx1 = x - gx.y;
        const float dx2 = x - gx.z;
        const float dx3 = x - gx.w;
        // row 0 (ey in .x/.z of e0,e1)
        a0 = min3(a0, fmaf(dx0, dx0, e0.x), fmaf(dx1, dx1, e0.z));
        b0 = min3(b0, fmaf(dx2, dx2, e1.x), fmaf(dx3, dx3, e1.z));
        // row 1 (ey in .y/.w)
        a1 = min3(a1, fmaf(dx0, dx0, e0.y), fmaf(dx1, dx1, e0.w));
        b1 = min3(b1, fmaf(dx2, dx2, e1.y), fmaf(dx3, dx3, e1.w));
        e0 = ne0; e1 = ne1; gx = ngx;
    }
    const float mind2r0 = fminf(a0, b0);
    const float mind2r1 = fminf(a1, b1);

    // ---- Phase B: thread owns m=tid; rank by t = d2*sc2 (sqrt-free,
    // monotone; dropped EPS*sc term is ~1e-6 where unclipped). 4 cols/iter,
    // scalar float4 sc2 reads with distance-1 prefetch; 24 VALU / 8 pairs.
    const float4* s0p = (const float4*)(sc2 + b * NN + r0 * WW);
    const float4* s1p = (const float4*)(sc2 + b * NN + (r0 + 1) * WW);
    float4 s0 = s0p[0], s1 = s1p[0];
    float dx0 = 0.0f - gxm;
    float dx1 = dx0 + nfX;
    float dx2 = dx0 + 2.0f * nfX;
    float dx3 = dx0 + 3.0f * nfX;
    const float step = 4.0f * nfX;
    float c0a = INFINITY, c0b = INFINITY;  // row0 chains
    float c1a = INFINITY, c1b = INFINITY;  // row1 chains
    #pragma unroll 2
    for (int k = 0; k < WW / 4; ++k) {
        const int kn = (k + 1) & 63;
        const float4 ns0 = s0p[kn];
        const float4 ns1 = s1p[kn];
        const float q0 = fmaf(dx0, dx0, ey0);
        const float q1 = fmaf(dx1, dx1, ey0);
        const float q2 = fmaf(dx2, dx2, ey0);
        const float q3 = fmaf(dx3, dx3, ey0);
        c0a = min3(c0a, q0 * s0.x, q1 * s0.y);
        c0b = min3(c0b, q2 * s0.z, q3 * s0.w);
        const float r0q = fmaf(dx0, dx0, ey1);
        const float r1q = fmaf(dx1, dx1, ey1);
        const float r2q = fmaf(dx2, dx2, ey1);
        const float r3q = fmaf(dx3, dx3, ey1);
        c1a = min3(c1a, r0q * s1.x, r1q * s1.y);
        c1b = min3(c1b, r2q * s1.z, r3q * s1.w);
        dx0 += step; dx1 += step; dx2 += step; dx3 += step;
        s0 = ns0; s1 = ns1;
    }
    const float tmin = fminf(fminf(c0a, c0b), fminf(c1a, c1b));
    const float cmin = asqrt(tmin);        // back to value space (one sqrt)

    // ---- term1 partials (thread-exclusive pixels), one wave reduce
    float sum0 = p0 + p1;
    float sum1 = fmaf(p0, asqrt(mind2r0), p1 * asqrt(mind2r1));
    #pragma unroll
    for (int off = 32; off; off >>= 1) {
        sum0 += __shfl_down(sum0, off, 64);
        sum1 += __shfl_down(sum1, off, 64);
    }
    if ((tid & 63) == 0) { swred[(tid >> 6) * 2] = sum0; swred[(tid >> 6) * 2 + 1] = sum1; }
    __syncthreads();

    // fire-and-forget merges — no fence, no counter, no waiting
    if (tid == 0) {
        const float s0r = (swred[0] + swred[2]) + (swred[4] + swred[6]);
        const float s1r = (swred[1] + swred[3]) + (swred[5] + swred[7]);
        atomicAdd(&sums[b * 2 + 0], s0r);
        atomicAdd(&sums[b * 2 + 1], s1r);
    }
    atomicMax(&gmin[b * MM + tid], ~__float_as_uint(cmin));
}

// ---------------------------------------------------------------------------
__global__ __launch_bounds__(256) void whd_final(const float* __restrict__ sums,
                                                 const unsigned* __restrict__ gmin,
                                                 float* __restrict__ out) {
    __shared__ float gred[4];
    const int tid = threadIdx.x;

    float gacc = 0.0f;
    #pragma unroll
    for (int q = 0; q < BB; ++q) {
        const float v = __uint_as_float(~gmin[q * MM + tid]);
        gacc += fminf(fmaxf(v, 0.0f), MAXD);
    }
    #pragma unroll
    for (int off = 32; off; off >>= 1) gacc += __shfl_down(gacc, off, 64);
    if ((tid & 63) == 0) gred[tid >> 6] = gacc;
    __syncthreads();
    if (tid == 0) {
        float t1 = 0.0f;
        #pragma unroll
        for (int q = 0; q < BB; ++q)
            t1 += sums[q * 2 + 1] / (sums[q * 2 + 0] + EPSI);
        const float g2 = (gred[0] + gred[1]) + (gred[2] + gred[3]);
        out[0] = t1 * (1.0f / BB) + g2 * (1.0f / (BB * MM));
    }
}

// ---------------------------------------------------------------------------
extern "C" void kernel_launch(void* const* d_in, const int* in_sizes, int n_in,
                              void* d_out, int out_size, void* d_ws, size_t ws_size,
                              hipStream_t stream) {
    const float* pm  = (const float*)d_in[0];   // [B, H, W]
    const float* gt  = (const float*)d_in[1];   // [B, M, 2]
    const float* osz = (const float*)d_in[2];   // [B, 2]
    float* out = (float*)d_out;

    unsigned* ws0  = (unsigned*)d_ws;
    float*    sums = (float*)ws0;
    unsigned* gmin = ws0 + WS_GMIN;
    float*    sc2  = (float*)(ws0 + WS_SC);
    float2*   gts  = (float2*)(ws0 + WS_GTS);
    float*    gxs  = (float*)(ws0 + WS_GXS);

    // zero-init sums + gmin only (0 == +inf in inverted representation)
    hipMemsetAsync(ws0, 0, (WS_GMIN + BB * MM) * sizeof(unsigned), stream);

    whd_prep<<<BB * NN / 256, 256, 0, stream>>>(pm, gt, osz, sc2, gts, gxs);

    dim3 grid(BLKS_PER_B, BB);
    whd_main<<<grid, 256, 0, stream>>>(pm, osz, sc2, gts, gxs, sums, gmin);

    whd_final<<<1, 256, 0, stream>>>(sums, gmin, out);
}